// Round 10
// baseline (13.410 us; speedup 1.0000x reference)
//
#include <hip/hip_runtime.h>
#include <math.h>

#define NN 2048
#define DD 64
#define BT 64             // 64x64 output tile
#define NB (NN / BT)      // 32 tiles per side; triangle = 528 blocks
#define LDK 72            // 64 bf16 + 8 pad = 144B row stride

typedef short short8 __attribute__((ext_vector_type(8)));   // 8 bf16 patterns (4 VGPR)
typedef float f32x4 __attribute__((ext_vector_type(4)));
typedef unsigned short us4 __attribute__((ext_vector_type(4)));

__device__ inline unsigned short f2bf(float f) {            // fp32 -> bf16 RNE
    unsigned u = __float_as_uint(f);
    return (unsigned short)((u + 0x7FFFu + ((u >> 16) & 1u)) >> 16);
}

// Symmetric cdist, single dispatch, triangle tiles stored twice.
// R10 change: PLAIN stores (not nontemporal). Output is 16.7MB = ~2.1MB/XCD,
// fits per-XCD L2; kernel completes at L2 write speed and HBM writeback
// overlaps subsequent replays instead of serializing inside the kernel.
// Diagonal exact 0; C/D layout verified R3/R4 (col=lane&15, row=(lane>>4)*4+reg).
__global__ __launch_bounds__(256, 6) void cdist_sym(const float* __restrict__ x,
                                                    float* __restrict__ out) {
    __shared__ unsigned short CA[BT][LDK];
    __shared__ unsigned short CB[BT][LDK];
    __shared__ float nrmA[BT], nrmB[BT];

    // ---- triangle decode: block t -> (u, v), u <= v ----
    int u = 0, rem = blockIdx.x, cnt = NB;
    while (rem >= cnt) { rem -= cnt; ++u; --cnt; }
    const int v = u + rem;
    const int bi = u * BT;
    const int bj = v * BT;

    const int tid = threadIdx.x;

    // ---- stage panels as bf16 + fused fp32 row norms ----
    #pragma unroll
    for (int p = 0; p < 2; ++p) {
        const float4* src = (const float4*)(x + (size_t)(p ? bj : bi) * DD);
        unsigned short (*C)[LDK] = p ? CB : CA;
        float* nr = p ? nrmB : nrmA;
        #pragma unroll
        for (int s = 0; s < 4; ++s) {
            int idx = tid + s * 256;
            int row = idx >> 4;
            int c4  = (idx & 15) << 2;
            float4 vv = src[idx];
            us4 hv = {f2bf(vv.x), f2bf(vv.y), f2bf(vv.z), f2bf(vv.w)};
            *(us4*)(&C[row][c4]) = hv;
            float sum = vv.x * vv.x;
            sum = fmaf(vv.y, vv.y, sum);
            sum = fmaf(vv.z, vv.z, sum);
            sum = fmaf(vv.w, vv.w, sum);
            sum += __shfl_xor(sum, 1, 16);
            sum += __shfl_xor(sum, 2, 16);
            sum += __shfl_xor(sum, 4, 16);
            sum += __shfl_xor(sum, 8, 16);
            if ((tid & 15) == 0) nr[row] = sum;
        }
    }
    __syncthreads();

    const int lane = tid & 63;
    const int wid  = tid >> 6;
    const int wm = wid >> 1, wn = wid & 1;   // 2x2 wave grid, 32x32 each
    const int lr = lane & 15;
    const int lk = (lane >> 4) * 8;

    // ---- gram: K=64 -> 8 ds_read_b128 + 8 MFMA per thread ----
    f32x4 acc[2][2] = {};
    #pragma unroll
    for (int ks = 0; ks < 2; ++ks) {
        const int k = ks * 32 + lk;
        short8 a0 = *(const short8*)(&CA[wm * 32 + lr][k]);
        short8 a1 = *(const short8*)(&CA[wm * 32 + 16 + lr][k]);
        short8 b0 = *(const short8*)(&CB[wn * 32 + lr][k]);
        short8 b1 = *(const short8*)(&CB[wn * 32 + 16 + lr][k]);
        acc[0][0] = __builtin_amdgcn_mfma_f32_16x16x32_bf16(a0, b0, acc[0][0], 0, 0, 0);
        acc[0][1] = __builtin_amdgcn_mfma_f32_16x16x32_bf16(a0, b1, acc[0][1], 0, 0, 0);
        acc[1][0] = __builtin_amdgcn_mfma_f32_16x16x32_bf16(a1, b0, acc[1][0], 0, 0, 0);
        acc[1][1] = __builtin_amdgcn_mfma_f32_16x16x32_bf16(a1, b1, acc[1][1], 0, 0, 0);
    }

    // ---- epilogue: d once, stored to (i,j) scalar + (j,i) f32x4 ----
    const float nb[2] = { nrmB[wn * 32 + lr], nrmB[wn * 32 + 16 + lr] };
    const int rbase = wm * 32 + (lane >> 4) * 4;            // + m*16 + g
    #pragma unroll
    for (int m = 0; m < 2; ++m) {
        #pragma unroll
        for (int n = 0; n < 2; ++n) {
            const int col = wn * 32 + n * 16 + lr;
            const int gj  = bj + col;
            f32x4 fd;
            #pragma unroll
            for (int g = 0; g < 4; ++g) {
                const int row = rbase + m * 16 + g;
                const int gi  = bi + row;
                float vv = nrmA[row] + nb[n] - 2.f * acc[m][n][g];
                float d = sqrtf(fmaxf(vv, 0.f));
                d = (gi == gj) ? 0.f : d;
                fd[g] = d;
                out[(size_t)gi * NN + gj] = d;
            }
            // transposed tile: 4 consecutive i at fixed j -> vector store
            *(f32x4*)(out + (size_t)gj * NN + bi + rbase + m * 16) = fd;
        }
    }
}

extern "C" void kernel_launch(void* const* d_in, const int* in_sizes, int n_in,
                              void* d_out, int out_size, void* d_ws, size_t ws_size,
                              hipStream_t stream) {
    const float* x = (const float*)d_in[0];
    float* out = (float*)d_out;
    cdist_sym<<<dim3(NB * (NB + 1) / 2), dim3(256), 0, stream>>>(x, out);
}

// Round 11
// 12.273 us; speedup vs baseline: 1.0927x; 1.0927x over previous
//
#include <hip/hip_runtime.h>
#include <math.h>

#define NN 2048
#define DD 64
#define BT 64             // 64x64 output tile
#define NB (NN / BT)      // 32 tiles per side; triangle = 528 blocks
#define LDK 72            // 64 bf16 + 8 pad = 144B row stride

typedef short short8 __attribute__((ext_vector_type(8)));   // 8 bf16 patterns (4 VGPR)
typedef float f32x4 __attribute__((ext_vector_type(4)));
typedef unsigned short us4 __attribute__((ext_vector_type(4)));

__device__ inline unsigned short f2bf(float f) {            // fp32 -> bf16 RNE
    unsigned u = __float_as_uint(f);
    return (unsigned short)((u + 0x7FFFu + ((u >> 16) & 1u)) >> 16);
}

// Symmetric cdist: upper-triangle tiles only (528 blocks), each tile stored
// twice: (i,j) scalar NT + (j,i) f32x4 NT. NT stores measured BETTER than
// plain (R9=12.29 vs R10=13.41 us): write-once data streams to HBM without
// L2 allocation/RFO traffic. G_ij==G_ji bitwise -> diagonal-block double
// writes benign; diagonal exact 0. C/D layout verified R3/R4.
__global__ __launch_bounds__(256, 6) void cdist_sym(const float* __restrict__ x,
                                                    float* __restrict__ out) {
    __shared__ unsigned short CA[BT][LDK];
    __shared__ unsigned short CB[BT][LDK];
    __shared__ float nrmA[BT], nrmB[BT];

    // ---- triangle decode: block t -> (u, v), u <= v ----
    int u = 0, rem = blockIdx.x, cnt = NB;
    while (rem >= cnt) { rem -= cnt; ++u; --cnt; }
    const int v = u + rem;
    const int bi = u * BT;
    const int bj = v * BT;

    const int tid = threadIdx.x;

    // ---- stage panels as bf16 + fused fp32 row norms ----
    #pragma unroll
    for (int p = 0; p < 2; ++p) {
        const float4* src = (const float4*)(x + (size_t)(p ? bj : bi) * DD);
        unsigned short (*C)[LDK] = p ? CB : CA;
        float* nr = p ? nrmB : nrmA;
        #pragma unroll
        for (int s = 0; s < 4; ++s) {
            int idx = tid + s * 256;
            int row = idx >> 4;
            int c4  = (idx & 15) << 2;
            float4 vv = src[idx];
            us4 hv = {f2bf(vv.x), f2bf(vv.y), f2bf(vv.z), f2bf(vv.w)};
            *(us4*)(&C[row][c4]) = hv;
            float sum = vv.x * vv.x;
            sum = fmaf(vv.y, vv.y, sum);
            sum = fmaf(vv.z, vv.z, sum);
            sum = fmaf(vv.w, vv.w, sum);
            sum += __shfl_xor(sum, 1, 16);
            sum += __shfl_xor(sum, 2, 16);
            sum += __shfl_xor(sum, 4, 16);
            sum += __shfl_xor(sum, 8, 16);
            if ((tid & 15) == 0) nr[row] = sum;
        }
    }
    __syncthreads();

    const int lane = tid & 63;
    const int wid  = tid >> 6;
    const int wm = wid >> 1, wn = wid & 1;   // 2x2 wave grid, 32x32 each
    const int lr = lane & 15;
    const int lk = (lane >> 4) * 8;

    // ---- gram: K=64 -> 8 ds_read_b128 + 8 MFMA per thread ----
    f32x4 acc[2][2] = {};
    #pragma unroll
    for (int ks = 0; ks < 2; ++ks) {
        const int k = ks * 32 + lk;
        short8 a0 = *(const short8*)(&CA[wm * 32 + lr][k]);
        short8 a1 = *(const short8*)(&CA[wm * 32 + 16 + lr][k]);
        short8 b0 = *(const short8*)(&CB[wn * 32 + lr][k]);
        short8 b1 = *(const short8*)(&CB[wn * 32 + 16 + lr][k]);
        acc[0][0] = __builtin_amdgcn_mfma_f32_16x16x32_bf16(a0, b0, acc[0][0], 0, 0, 0);
        acc[0][1] = __builtin_amdgcn_mfma_f32_16x16x32_bf16(a0, b1, acc[0][1], 0, 0, 0);
        acc[1][0] = __builtin_amdgcn_mfma_f32_16x16x32_bf16(a1, b0, acc[1][0], 0, 0, 0);
        acc[1][1] = __builtin_amdgcn_mfma_f32_16x16x32_bf16(a1, b1, acc[1][1], 0, 0, 0);
    }

    // ---- epilogue: d once, stored to (i,j) scalar NT + (j,i) f32x4 NT ----
    const float nb[2] = { nrmB[wn * 32 + lr], nrmB[wn * 32 + 16 + lr] };
    const int rbase = wm * 32 + (lane >> 4) * 4;            // + m*16 + g
    #pragma unroll
    for (int m = 0; m < 2; ++m) {
        #pragma unroll
        for (int n = 0; n < 2; ++n) {
            const int col = wn * 32 + n * 16 + lr;
            const int gj  = bj + col;
            f32x4 fd;
            #pragma unroll
            for (int g = 0; g < 4; ++g) {
                const int row = rbase + m * 16 + g;
                const int gi  = bi + row;
                float vv = nrmA[row] + nb[n] - 2.f * acc[m][n][g];
                float d = sqrtf(fmaxf(vv, 0.f));
                d = (gi == gj) ? 0.f : d;
                fd[g] = d;
                __builtin_nontemporal_store(d, out + (size_t)gi * NN + gj);
            }
            // transposed tile: 4 consecutive i at fixed j -> vector store
            __builtin_nontemporal_store(
                fd, (f32x4*)(out + (size_t)gj * NN + bi + rbase + m * 16));
        }
    }
}

extern "C" void kernel_launch(void* const* d_in, const int* in_sizes, int n_in,
                              void* d_out, int out_size, void* d_ws, size_t ws_size,
                              hipStream_t stream) {
    const float* x = (const float*)d_in[0];
    float* out = (float*)d_out;
    cdist_sym<<<dim3(NB * (NB + 1) / 2), dim3(256), 0, stream>>>(x, out);
}